// Round 4
// baseline (300.409 us; speedup 1.0000x reference)
//
#include <hip/hip_runtime.h>

typedef __attribute__((ext_vector_type(8))) short bf16x8;
typedef __attribute__((ext_vector_type(4))) float f32x4;

#define B_  2
#define S_  2048
#define DM  512
#define KD  256
#define HD  32
#define NH  8

__device__ __forceinline__ float bf2f(ushort u) {
    return __uint_as_float(((uint)u) << 16);
}
__device__ __forceinline__ ushort f2bf(float f) {
    uint x = __float_as_uint(f);
    return (ushort)((x + 0x7fffu + ((x >> 16) & 1u)) >> 16);  // RNE
}
#define MFMA __builtin_amdgcn_mfma_f32_16x16x32_bf16

// dtype detector (R1 evidence: fp32 inputs; kept as insurance)
__global__ void detect_dtype(const ushort* __restrict__ q, int* __restrict__ flag)
{
    if (threadIdx.x == 0 && blockIdx.x == 0) {
        int cnt = 0;
        for (int i = 0; i < 256; ++i) {
            int e = (q[i] >> 7) & 0xFF;
            if (e >= 100 && e <= 133) ++cnt;
        }
        *flag = (cnt >= 230) ? 1 : 0;
    }
}

// ---- one-time convert: X->bf16 rowmajor, W->W^T bf16, biases->fp32
__global__ __launch_bounds__(256) void convert_all(
    const void* __restrict__ Q, const void* __restrict__ K, const void* __restrict__ V,
    const void* __restrict__ Wq, const void* __restrict__ bq,
    const void* __restrict__ Wk, const void* __restrict__ bk,
    const void* __restrict__ Wv, const void* __restrict__ bv,
    const void* __restrict__ Wo, const void* __restrict__ bo,
    const int* __restrict__ flag,
    ushort* __restrict__ Xb, ushort* __restrict__ Wt, ushort* __restrict__ Wot,
    float* __restrict__ biasf)
{
    int isbf = *flag;
    int y = blockIdx.y;
    int tid = blockIdx.x * 256 + threadIdx.x;      // grid.x=1024 -> 262144 threads
    if (y < 3) {
        const void* X = (y == 0) ? Q : (y == 1) ? K : V;
        ushort* dst = Xb + (size_t)y * (4096 * 512) + (size_t)tid * 8;
        if (isbf) {
            *(bf16x8*)dst = *((const bf16x8*)X + tid);
        } else {
            const float* s = (const float*)X + (size_t)tid * 8;
            bf16x8 v8;
            #pragma unroll
            for (int j = 0; j < 8; ++j) v8[j] = (short)f2bf(s[j]);
            *(bf16x8*)dst = v8;
        }
    } else {
        for (int e = tid; e < 525568; e += 262144) {
            if (e < 393216) {
                int m = e >> 17;
                int i = e & 131071;
                int n = i >> 9, k = i & 511;
                const void* W = (m == 0) ? Wq : (m == 1) ? Wk : Wv;
                float v = isbf ? bf2f(((const ushort*)W)[k * KD + n]) : ((const float*)W)[k * KD + n];
                Wt[(size_t)m * 131072 + n * 512 + k] = f2bf(v);
            } else if (e < 524288) {
                int i = e - 393216;
                int n = i >> 8, k = i & 255;
                float v = isbf ? bf2f(((const ushort*)Wo)[k * DM + n]) : ((const float*)Wo)[k * DM + n];
                Wot[n * 256 + k] = f2bf(v);
            } else {
                int i = e - 524288;
                const void* bp; int off;
                if (i < 256)      { bp = bq; off = i; }
                else if (i < 512) { bp = bk; off = i - 256; }
                else if (i < 768) { bp = bv; off = i - 512; }
                else              { bp = bo; off = i - 768; }
                biasf[i] = isbf ? bf2f(((const ushort*)bp)[off]) : ((const float*)bp)[off];
            }
        }
    }
}

// ---- QKV GEMM: per wave 64x64 tile, A & B frags are contiguous bf16x8 loads
__global__ __launch_bounds__(256) void qkv_gemm(
    const ushort* __restrict__ Xb, const ushort* __restrict__ Wt,
    const float* __restrict__ biasf,
    ushort* __restrict__ qh, ushort* __restrict__ kh, ushort* __restrict__ vh)
{
    int y = blockIdx.y;
    int wave = threadIdx.x >> 6, lane = threadIdx.x & 63;
    int l16 = lane & 15, quad = lane >> 4;
    int m0 = blockIdx.x * 64;
    int n0 = wave * 64;
    const ushort* X = Xb + (size_t)y * (4096 * 512);
    const ushort* W = Wt + (size_t)y * (256 * 512);
    f32x4 acc[4][4] = {};
    for (int ks = 0; ks < 512; ks += 32) {
        bf16x8 a[4], b[4];
        #pragma unroll
        for (int i = 0; i < 4; ++i)
            a[i] = *(const bf16x8*)(X + (size_t)(m0 + 16 * i + l16) * 512 + ks + quad * 8);
        #pragma unroll
        for (int j = 0; j < 4; ++j)
            b[j] = *(const bf16x8*)(W + (size_t)(n0 + 16 * j + l16) * 512 + ks + quad * 8);
        #pragma unroll
        for (int i = 0; i < 4; ++i)
            #pragma unroll
            for (int j = 0; j < 4; ++j)
                acc[i][j] = MFMA(a[i], b[j], acc[i][j], 0, 0, 0);
    }
    ushort* out = (y == 0) ? qh : (y == 1) ? kh : vh;
    #pragma unroll
    for (int i = 0; i < 4; ++i) {
        #pragma unroll
        for (int j = 0; j < 4; ++j) {
            int n = n0 + 16 * j + l16;
            float bs = biasf[y * 256 + n];
            int h = n >> 5, d = n & 31;
            #pragma unroll
            for (int r = 0; r < 4; ++r) {
                int rg = m0 + 16 * i + quad * 4 + r;
                int bb = rg >> 11, ss = rg & 2047;
                out[((((size_t)bb * NH + h) * S_ + ss) << 5) + d] = f2bf(acc[i][j][r] + bs);
            }
        }
    }
}

// ---- transpose V heads: [bh][s][d] -> [bh][d][s]
__global__ __launch_bounds__(256) void transpose_v(
    const ushort* __restrict__ vh, ushort* __restrict__ vT)
{
    __shared__ ushort lds[32][66];
    int bh = blockIdx.x >> 5;
    int s0 = (blockIdx.x & 31) * 64;
    int t = threadIdx.x;
    const ushort* src = vh + ((size_t)bh * S_ + s0) * HD;
    #pragma unroll
    for (int it = 0; it < 8; ++it) {
        int e = it * 256 + t;               // e = s'*32 + d
        lds[e & 31][e >> 5] = src[e];
    }
    __syncthreads();
    ushort* dst = vT + (size_t)bh * HD * S_ + s0;
    #pragma unroll
    for (int it = 0; it < 8; ++it) {
        int e = it * 256 + t;               // e = d*64 + s'
        dst[(size_t)(e >> 6) * S_ + (e & 63)] = lds[e >> 6][e & 63];
    }
}

// ---- attention, no-max-shift softmax, split over 2 k-chunks
__global__ __launch_bounds__(256) void attn(
    const ushort* __restrict__ qh, const ushort* __restrict__ kh,
    const ushort* __restrict__ vT, const void* __restrict__ maskp,
    const int* __restrict__ flag, float* __restrict__ pO, float* __restrict__ pl)
{
    __shared__ __align__(16) ushort ldsP[4][16][68];
    int isbf = *flag;
    int wave = threadIdx.x >> 6, lane = threadIdx.x & 63;
    int l16 = lane & 15, quad = lane >> 4;
    int wid = blockIdx.x * 4 + wave;        // 4096 waves
    int chunk = wid & 1, qt = (wid >> 1) & 127, bh = wid >> 8;
    int b = bh >> 3;
    int q0 = qt * 16;
    const ushort* qb = qh + (size_t)bh * S_ * HD;
    const ushort* kb = kh + (size_t)bh * S_ * HD;
    const ushort* vb = vT + (size_t)bh * HD * S_;
    const ushort* mbb = (const ushort*)maskp + (size_t)b * S_ * S_;
    const float*  mbf = (const float*)maskp  + (size_t)b * S_ * S_;

    bf16x8 aq = *(const bf16x8*)(qb + (size_t)(q0 + l16) * HD + quad * 8);
    f32x4 O0 = {0, 0, 0, 0}, O1 = {0, 0, 0, 0};
    const f32x4 zero = {0, 0, 0, 0};
    float lsum[4] = {0, 0, 0, 0};

    int kend = chunk * 1024 + 1024;
    for (int k0 = chunk * 1024; k0 < kend; k0 += 64) {
        f32x4 Sc[4];
        #pragma unroll
        for (int c = 0; c < 4; ++c) {
            bf16x8 bk = *(const bf16x8*)(kb + (size_t)(k0 + c * 16 + l16) * HD + quad * 8);
            Sc[c] = MFMA(aq, bk, zero, 0, 0, 0);
        }
        #pragma unroll
        for (int c = 0; c < 4; ++c) {
            #pragma unroll
            for (int r = 0; r < 4; ++r) {
                size_t mo = (size_t)(q0 + quad * 4 + r) * S_ + k0 + c * 16 + l16;
                float mv = isbf ? bf2f(mbb[mo]) : mbf[mo];
                float s = fminf(Sc[c][r] * 0.0625f + mv, 30.0f);
                float p = __expf(s);
                lsum[r] += p;
                ldsP[wave][quad * 4 + r][c * 16 + l16] = f2bf(p);
            }
        }
        __syncthreads();
        bf16x8 aP0, aP1;
        {
            const ushort* base = &ldsP[wave][l16][0];
            ((ushort4*)&aP0)[0] = *(const ushort4*)(base + quad * 8);
            ((ushort4*)&aP0)[1] = *(const ushort4*)(base + quad * 8 + 4);
            ((ushort4*)&aP1)[0] = *(const ushort4*)(base + 32 + quad * 8);
            ((ushort4*)&aP1)[1] = *(const ushort4*)(base + 32 + quad * 8 + 4);
        }
        const ushort* v0 = vb + (size_t)l16 * S_ + k0 + quad * 8;
        const ushort* v1 = vb + (size_t)(16 + l16) * S_ + k0 + quad * 8;
        bf16x8 bv00 = *(const bf16x8*)(v0);
        bf16x8 bv01 = *(const bf16x8*)(v0 + 32);
        bf16x8 bv10 = *(const bf16x8*)(v1);
        bf16x8 bv11 = *(const bf16x8*)(v1 + 32);
        O0 = MFMA(aP0, bv00, O0, 0, 0, 0);
        O0 = MFMA(aP1, bv01, O0, 0, 0, 0);
        O1 = MFMA(aP0, bv10, O1, 0, 0, 0);
        O1 = MFMA(aP1, bv11, O1, 0, 0, 0);
        __syncthreads();
    }
    float* po = pO + (size_t)wid * 512;     // [wid][row16][d32]
    #pragma unroll
    for (int r = 0; r < 4; ++r) {
        int row = quad * 4 + r;
        po[row * 32 + l16]      = O0[r];
        po[row * 32 + 16 + l16] = O1[r];
        float sthis = lsum[r];
        #pragma unroll
        for (int off = 8; off; off >>= 1) sthis += __shfl_xor(sthis, off, 16);
        if (l16 == 0) pl[wid * 16 + row] = sthis;
    }
}

// ---- combine 2 chunk-partials, normalize, write ctx bf16 [b*s][h*32+d]
__global__ __launch_bounds__(256) void combine(
    const float* __restrict__ pO, const float* __restrict__ pl, ushort* __restrict__ ctx)
{
    int e = blockIdx.x * 256 + threadIdx.x;  // 1,048,576
    int d = e & 31;
    int row = (e >> 5) & 2047;
    int bh = e >> 16;
    int qt = row >> 4, r16 = row & 15;
    int wid0 = (bh << 8) | (qt << 1);
    float o = pO[(size_t)wid0 * 512 + r16 * 32 + d] + pO[(size_t)(wid0 + 1) * 512 + r16 * 32 + d];
    float l = pl[wid0 * 16 + r16] + pl[(wid0 + 1) * 16 + r16];
    int b = bh >> 3, h = bh & 7;
    ctx[((size_t)(b * S_ + row)) * KD + h * HD + d] = f2bf(o / l);
}

// ---- out projection: ctx[4096,256] @ Wo[256,512] + bo -> fp32 out
__global__ __launch_bounds__(256) void out_proj(
    const ushort* __restrict__ ctx, const ushort* __restrict__ Wot,
    const float* __restrict__ biasf, float* __restrict__ out)
{
    int wave = threadIdx.x >> 6, lane = threadIdx.x & 63;
    int l16 = lane & 15, quad = lane >> 4;
    int m0 = (blockIdx.x >> 1) * 64;
    int n0 = (blockIdx.x & 1) * 256 + wave * 64;
    f32x4 acc[4][4] = {};
    for (int ks = 0; ks < 256; ks += 32) {
        bf16x8 a[4], b[4];
        #pragma unroll
        for (int i = 0; i < 4; ++i)
            a[i] = *(const bf16x8*)(ctx + (size_t)(m0 + 16 * i + l16) * 256 + ks + quad * 8);
        #pragma unroll
        for (int j = 0; j < 4; ++j)
            b[j] = *(const bf16x8*)(Wot + (size_t)(n0 + 16 * j + l16) * 256 + ks + quad * 8);
        #pragma unroll
        for (int i = 0; i < 4; ++i)
            #pragma unroll
            for (int j = 0; j < 4; ++j)
                acc[i][j] = MFMA(a[i], b[j], acc[i][j], 0, 0, 0);
    }
    #pragma unroll
    for (int i = 0; i < 4; ++i) {
        #pragma unroll
        for (int j = 0; j < 4; ++j) {
            int n = n0 + 16 * j + l16;
            float bs = biasf[768 + n];
            #pragma unroll
            for (int r = 0; r < 4; ++r) {
                int rg = m0 + 16 * i + quad * 4 + r;
                out[(size_t)rg * DM + n] = acc[i][j][r] + bs;
            }
        }
    }
}

extern "C" void kernel_launch(void* const* d_in, const int* in_sizes, int n_in,
                              void* d_out, int out_size, void* d_ws, size_t ws_size,
                              hipStream_t stream)
{
    const void* V    = d_in[0];
    const void* Q    = d_in[1];
    const void* K    = d_in[2];
    const void* mask = d_in[3];
    const void* Wq = d_in[4];  const void* bq = d_in[5];
    const void* Wk = d_in[6];  const void* bk = d_in[7];
    const void* Wv = d_in[8];  const void* bv = d_in[9];
    const void* Wo = d_in[10]; const void* bo = d_in[11];
    float* out = (float*)d_out;

    char* ws = (char*)d_ws;
    int*    flagp = (int*)ws;                      // 128 B
    float*  biasf = (float*)(ws + 128);            // 1280 fp32
    ushort* qh  = (ushort*)(ws + 8192);            // each 1,048,576 ushorts (2 MB)
    ushort* kh  = qh  + 1048576;
    ushort* vh_ = kh  + 1048576;
    ushort* vT  = vh_ + 1048576;
    ushort* ctx = vT  + 1048576;
    ushort* Wt  = ctx + 1048576;                   // 393,216
    ushort* Wot = Wt  + 393216;                    // 131,072
    ushort* Xb  = Wot + 131072;                    // 6,291,456 ushorts (12.6 MB)
    // partials overlap Xb (Xb dead after qkv_gemm): 8.65 MB <= 12.6 MB
    float* pO = (float*)Xb;                        // 4096 waves x 512 fp32
    float* pl = pO + 4096 * 512;                   // 65,536 fp32

    detect_dtype<<<1, 64, 0, stream>>>((const ushort*)Q, flagp);
    convert_all<<<dim3(1024, 4), 256, 0, stream>>>(Q, K, V, Wq, bq, Wk, bk, Wv, bv, Wo, bo,
                                                   flagp, Xb, Wt, Wot, biasf);
    qkv_gemm<<<dim3(64, 3), 256, 0, stream>>>(Xb, Wt, biasf, qh, kh, vh_);
    transpose_v<<<512, 256, 0, stream>>>(vh_, vT);
    attn<<<1024, 256, 0, stream>>>(qh, kh, vT, mask, flagp, pO, pl);
    combine<<<4096, 256, 0, stream>>>(pO, pl, ctx);
    out_proj<<<128, 256, 0, stream>>>(ctx, Wot, biasf, out);
}

// Round 5
// 210.748 us; speedup vs baseline: 1.4254x; 1.4254x over previous
//
#include <hip/hip_runtime.h>

typedef __attribute__((ext_vector_type(8))) short bf16x8;
typedef __attribute__((ext_vector_type(4))) float f32x4;

#define B_  2
#define S_  2048
#define DM  512
#define KD  256
#define HD  32
#define NH  8

__device__ __forceinline__ float bf2f(ushort u) {
    return __uint_as_float(((uint)u) << 16);
}
__device__ __forceinline__ ushort f2bf(float f) {
    uint x = __float_as_uint(f);
    return (ushort)((x + 0x7fffu + ((x >> 16) & 1u)) >> 16);  // RNE
}
#define MFMA __builtin_amdgcn_mfma_f32_16x16x32_bf16

// dtype detector, parallel across one wave (R1 evidence: fp32 inputs)
__global__ void detect_dtype(const ushort* __restrict__ q, int* __restrict__ flag)
{
    int lane = threadIdx.x & 63;
    int cnt = 0;
    for (int i = lane; i < 256; i += 64) {
        int e = (q[i] >> 7) & 0xFF;
        if (e >= 100 && e <= 133) ++cnt;
    }
    #pragma unroll
    for (int off = 32; off; off >>= 1) cnt += __shfl_down(cnt, off, 64);
    if (lane == 0) *flag = (cnt >= 230) ? 1 : 0;
}

// ---- convert Q,K,V fp32->bf16 row-major (coalesced float4 in, bf16x8 out)
__global__ __launch_bounds__(256) void convert_x(
    const void* __restrict__ Q, const void* __restrict__ K, const void* __restrict__ V,
    const int* __restrict__ flag, ushort* __restrict__ Xb)
{
    int isbf = *flag;
    int y = blockIdx.y;
    int tid = blockIdx.x * 256 + threadIdx.x;      // 262144 per tensor
    const void* X = (y == 0) ? Q : (y == 1) ? K : V;
    ushort* dst = Xb + (size_t)y * (4096 * 512) + (size_t)tid * 8;
    if (isbf) {
        *(bf16x8*)dst = *((const bf16x8*)X + tid);
    } else {
        const float* s = (const float*)X + (size_t)tid * 8;
        bf16x8 v8;
        #pragma unroll
        for (int j = 0; j < 8; ++j) v8[j] = (short)f2bf(s[j]);
        *(bf16x8*)dst = v8;
    }
}

// ---- LDS-tiled transpose of Wq/Wk/Wv ([512,256]->[256,512]) and Wo ([256,512]->[512,256]?
//      no: Wot is [n=512? ] Wo[256,512] -> Wot[512rows? n][256 k]) + biases
__global__ __launch_bounds__(256) void transpose_w(
    const void* __restrict__ Wq, const void* __restrict__ Wk, const void* __restrict__ Wv,
    const void* __restrict__ Wo,
    const void* __restrict__ bq, const void* __restrict__ bk,
    const void* __restrict__ bv, const void* __restrict__ bo,
    const int* __restrict__ flag,
    ushort* __restrict__ Wt, ushort* __restrict__ Wot, float* __restrict__ biasf)
{
    int isbf = *flag;
    int bid = blockIdx.x;
    if (bid >= 512) {            // biases -> fp32
        for (int i = threadIdx.x; i < 1280; i += 256) {
            const void* bp; int off;
            if (i < 256)      { bp = bq; off = i; }
            else if (i < 512) { bp = bk; off = i - 256; }
            else if (i < 768) { bp = bv; off = i - 512; }
            else              { bp = bo; off = i - 768; }
            biasf[i] = isbf ? bf2f(((const ushort*)bp)[off]) : ((const float*)bp)[off];
        }
        return;
    }
    const void* W; int R, C; ushort* T;
    int m = bid >> 7, tix = bid & 127;
    if (m < 3) { W = (m == 0) ? Wq : (m == 1) ? Wk : Wv; R = 512; C = 256; T = Wt + m * 131072; }
    else       { W = Wo; R = 256; C = 512; T = Wot; }
    int tilesPerRow = C >> 5;
    int r0 = (tix / tilesPerRow) * 32, c0 = (tix % tilesPerRow) * 32;
    __shared__ float lds[32][33];
    int t = threadIdx.x;
    int rr = t >> 3, cc = (t & 7) * 4;
    if (isbf) {
        const ushort* Ws = (const ushort*)W;
        #pragma unroll
        for (int j = 0; j < 4; ++j) lds[rr][cc + j] = bf2f(Ws[(size_t)(r0 + rr) * C + c0 + cc + j]);
    } else {
        float4 v = *(const float4*)((const float*)W + (size_t)(r0 + rr) * C + c0 + cc);
        lds[rr][cc + 0] = v.x; lds[rr][cc + 1] = v.y; lds[rr][cc + 2] = v.z; lds[rr][cc + 3] = v.w;
    }
    __syncthreads();
    ushort4 o;
    o.x = f2bf(lds[cc + 0][rr]); o.y = f2bf(lds[cc + 1][rr]);
    o.z = f2bf(lds[cc + 2][rr]); o.w = f2bf(lds[cc + 3][rr]);
    *(ushort4*)(T + (size_t)(c0 + rr) * R + r0 + cc) = o;
}

// ---- QKV GEMM: per wave 32x64 tile; A/B frags contiguous bf16x8
__global__ __launch_bounds__(256) void qkv_gemm(
    const ushort* __restrict__ Xb, const ushort* __restrict__ Wt,
    const float* __restrict__ biasf,
    ushort* __restrict__ qh, ushort* __restrict__ kh, ushort* __restrict__ vh)
{
    int y = blockIdx.y;
    int wave = threadIdx.x >> 6, lane = threadIdx.x & 63;
    int l16 = lane & 15, quad = lane >> 4;
    int m0 = blockIdx.x * 32;           // grid.x = 128
    int n0 = wave * 64;
    const ushort* X = Xb + (size_t)y * (4096 * 512);
    const ushort* W = Wt + (size_t)y * (256 * 512);
    f32x4 acc[2][4] = {};
    for (int ks = 0; ks < 512; ks += 32) {
        bf16x8 a[2], b[4];
        #pragma unroll
        for (int i = 0; i < 2; ++i)
            a[i] = *(const bf16x8*)(X + (size_t)(m0 + 16 * i + l16) * 512 + ks + quad * 8);
        #pragma unroll
        for (int j = 0; j < 4; ++j)
            b[j] = *(const bf16x8*)(W + (size_t)(n0 + 16 * j + l16) * 512 + ks + quad * 8);
        #pragma unroll
        for (int i = 0; i < 2; ++i)
            #pragma unroll
            for (int j = 0; j < 4; ++j)
                acc[i][j] = MFMA(a[i], b[j], acc[i][j], 0, 0, 0);
    }
    ushort* out = (y == 0) ? qh : (y == 1) ? kh : vh;
    #pragma unroll
    for (int i = 0; i < 2; ++i) {
        #pragma unroll
        for (int j = 0; j < 4; ++j) {
            int n = n0 + 16 * j + l16;
            float bs = biasf[y * 256 + n];
            int h = n >> 5, d = n & 31;
            #pragma unroll
            for (int r = 0; r < 4; ++r) {
                int rg = m0 + 16 * i + quad * 4 + r;
                int bb = rg >> 11, ss = rg & 2047;
                out[((((size_t)bb * NH + h) * S_ + ss) << 5) + d] = f2bf(acc[i][j][r] + bs);
            }
        }
    }
}

// ---- transpose V heads: [bh][s][d] -> [bh][d][s]
__global__ __launch_bounds__(256) void transpose_v(
    const ushort* __restrict__ vh, ushort* __restrict__ vT)
{
    __shared__ ushort lds[32][66];
    int bh = blockIdx.x >> 5;
    int s0 = (blockIdx.x & 31) * 64;
    int t = threadIdx.x;
    const ushort* src = vh + ((size_t)bh * S_ + s0) * HD;
    #pragma unroll
    for (int it = 0; it < 8; ++it) {
        int e = it * 256 + t;
        lds[e & 31][e >> 5] = src[e];
    }
    __syncthreads();
    ushort* dst = vT + (size_t)bh * HD * S_ + s0;
    #pragma unroll
    for (int it = 0; it < 8; ++it) {
        int e = it * 256 + t;
        dst[(size_t)(e >> 6) * S_ + (e & 63)] = lds[e >> 6][e & 63];
    }
}

// ---- attention: barrier-free, register-pipelined, vectorized mask via LDS
__global__ __launch_bounds__(256) void attn(
    const ushort* __restrict__ qh, const ushort* __restrict__ kh,
    const ushort* __restrict__ vT, const void* __restrict__ maskp,
    const int* __restrict__ flag, float* __restrict__ pO, float* __restrict__ pl)
{
    __shared__ __align__(16) float  ldsM[4][16][68];   // stride 272B (16B-mult)
    __shared__ __align__(16) ushort ldsP[4][16][72];   // stride 144B (16B-mult)
    int isbf = *flag;
    int wave = threadIdx.x >> 6, lane = threadIdx.x & 63;
    int l16 = lane & 15, quad = lane >> 4;
    int wid = blockIdx.x * 4 + wave;        // 4096 waves
    int chunk = wid & 1, qt = (wid >> 1) & 127, bh = wid >> 8;
    int b = bh >> 3;
    int q0 = qt * 16;
    const ushort* qb = qh + (size_t)bh * S_ * HD;
    const ushort* kb = kh + (size_t)bh * S_ * HD;
    const ushort* vb = vT + (size_t)bh * HD * S_;
    const ushort* mbb = (const ushort*)maskp + (size_t)b * S_ * S_;
    const float*  mbf = (const float*)maskp  + (size_t)b * S_ * S_;

    bf16x8 aq = *(const bf16x8*)(qb + (size_t)(q0 + l16) * HD + quad * 8);
    f32x4 O0 = {0, 0, 0, 0}, O1 = {0, 0, 0, 0};
    const f32x4 zero = {0, 0, 0, 0};
    float lsum[4] = {0, 0, 0, 0};

    auto loadT = [&](int k0, float4* M, bf16x8* Kf, bf16x8* Vf) {
        if (isbf) {
            #pragma unroll
            for (int it = 0; it < 4; ++it) {
                ushort4 u = *(const ushort4*)(mbb + (size_t)(q0 + it * 4 + quad) * S_ + k0 + l16 * 4);
                float4 f; f.x = bf2f(u.x); f.y = bf2f(u.y); f.z = bf2f(u.z); f.w = bf2f(u.w);
                M[it] = f;
            }
        } else {
            #pragma unroll
            for (int it = 0; it < 4; ++it)
                M[it] = *(const float4*)(mbf + (size_t)(q0 + it * 4 + quad) * S_ + k0 + l16 * 4);
        }
        #pragma unroll
        for (int c = 0; c < 4; ++c)
            Kf[c] = *(const bf16x8*)(kb + (size_t)(k0 + c * 16 + l16) * HD + quad * 8);
        Vf[0] = *(const bf16x8*)(vb + (size_t)l16 * S_ + k0 + quad * 8);
        Vf[1] = *(const bf16x8*)(vb + (size_t)l16 * S_ + k0 + 32 + quad * 8);
        Vf[2] = *(const bf16x8*)(vb + (size_t)(16 + l16) * S_ + k0 + quad * 8);
        Vf[3] = *(const bf16x8*)(vb + (size_t)(16 + l16) * S_ + k0 + 32 + quad * 8);
    };

    auto tilestep = [&](float4* M, bf16x8* Kf, bf16x8* Vf,
                        int nextk0, float4* Mn, bf16x8* Kn, bf16x8* Vn) {
        #pragma unroll
        for (int it = 0; it < 4; ++it)
            *(float4*)&ldsM[wave][it * 4 + quad][l16 * 4] = M[it];
        if (nextk0 >= 0) loadT(nextk0, Mn, Kn, Vn);   // prefetch (no wait)
        f32x4 Sc[4];
        #pragma unroll
        for (int c = 0; c < 4; ++c) Sc[c] = MFMA(aq, Kf[c], zero, 0, 0, 0);
        asm volatile("s_waitcnt lgkmcnt(0)" ::: "memory");   // mask writes visible (wave-private)
        #pragma unroll
        for (int c = 0; c < 4; ++c) {
            #pragma unroll
            for (int r = 0; r < 4; ++r) {
                float mv = ldsM[wave][quad * 4 + r][c * 16 + l16];
                float s = fminf(Sc[c][r] * 0.0625f + mv, 30.0f);
                float p = __expf(s);
                lsum[r] += p;
                ldsP[wave][quad * 4 + r][c * 16 + l16] = f2bf(p);
            }
        }
        asm volatile("s_waitcnt lgkmcnt(0)" ::: "memory");   // P writes visible
        bf16x8 aP0 = *(const bf16x8*)&ldsP[wave][l16][quad * 8];
        bf16x8 aP1 = *(const bf16x8*)&ldsP[wave][l16][32 + quad * 8];
        O0 = MFMA(aP0, Vf[0], O0, 0, 0, 0);
        O0 = MFMA(aP1, Vf[1], O0, 0, 0, 0);
        O1 = MFMA(aP0, Vf[2], O1, 0, 0, 0);
        O1 = MFMA(aP1, Vf[3], O1, 0, 0, 0);
    };

    int kbase = chunk * 1024;
    float4 Ma[4], Mb2[4]; bf16x8 Ka[4], Kb2[4], Va[4], Vb2[4];
    loadT(kbase, Ma, Ka, Va);
    for (int t = 0; t < 16; t += 2) {
        tilestep(Ma, Ka, Va, kbase + (t + 1) * 64, Mb2, Kb2, Vb2);
        tilestep(Mb2, Kb2, Vb2, (t + 2 < 16) ? kbase + (t + 2) * 64 : -1, Ma, Ka, Va);
    }

    float* po = pO + (size_t)wid * 512;     // [wid][row16][d32]
    #pragma unroll
    for (int r = 0; r < 4; ++r) {
        int row = quad * 4 + r;
        po[row * 32 + l16]      = O0[r];
        po[row * 32 + 16 + l16] = O1[r];
        float sthis = lsum[r];
        #pragma unroll
        for (int off = 8; off; off >>= 1) sthis += __shfl_xor(sthis, off, 16);
        if (l16 == 0) pl[wid * 16 + row] = sthis;
    }
}

// ---- combine 2 chunk-partials, normalize, write ctx bf16 [b*s][h*32+d]
__global__ __launch_bounds__(256) void combine(
    const float* __restrict__ pO, const float* __restrict__ pl, ushort* __restrict__ ctx)
{
    int e = blockIdx.x * 256 + threadIdx.x;  // 1,048,576
    int d = e & 31;
    int row = (e >> 5) & 2047;
    int bh = e >> 16;
    int qt = row >> 4, r16 = row & 15;
    int wid0 = (bh << 8) | (qt << 1);
    float o = pO[(size_t)wid0 * 512 + r16 * 32 + d] + pO[(size_t)(wid0 + 1) * 512 + r16 * 32 + d];
    float l = pl[wid0 * 16 + r16] + pl[(wid0 + 1) * 16 + r16];
    int b = bh >> 3, h = bh & 7;
    ctx[((size_t)(b * S_ + row)) * KD + h * HD + d] = f2bf(o / l);
}

// ---- out projection: ctx[4096,256] @ Wo^T + bo -> fp32 out; 32x64/wave
__global__ __launch_bounds__(256) void out_proj(
    const ushort* __restrict__ ctx, const ushort* __restrict__ Wot,
    const float* __restrict__ biasf, float* __restrict__ out)
{
    int wave = threadIdx.x >> 6, lane = threadIdx.x & 63;
    int l16 = lane & 15, quad = lane >> 4;
    int m0 = (blockIdx.x >> 1) * 32;                  // grid = 256
    int n0 = (blockIdx.x & 1) * 256 + wave * 64;
    f32x4 acc[2][4] = {};
    for (int ks = 0; ks < 256; ks += 32) {
        bf16x8 a[2], b[4];
        #pragma unroll
        for (int i = 0; i < 2; ++i)
            a[i] = *(const bf16x8*)(ctx + (size_t)(m0 + 16 * i + l16) * 256 + ks + quad * 8);
        #pragma unroll
        for (int j = 0; j < 4; ++j)
            b[j] = *(const bf16x8*)(Wot + (size_t)(n0 + 16 * j + l16) * 256 + ks + quad * 8);
        #pragma unroll
        for (int i = 0; i < 2; ++i)
            #pragma unroll
            for (int j = 0; j < 4; ++j)
                acc[i][j] = MFMA(a[i], b[j], acc[i][j], 0, 0, 0);
    }
    #pragma unroll
    for (int i = 0; i < 2; ++i) {
        #pragma unroll
        for (int j = 0; j < 4; ++j) {
            int n = n0 + 16 * j + l16;
            float bs = biasf[768 + n];
            #pragma unroll
            for (int r = 0; r < 4; ++r) {
                int rg = m0 + 16 * i + quad * 4 + r;
                out[(size_t)rg * DM + n] = acc[i][j][r] + bs;
            }
        }
    }
}

extern "C" void kernel_launch(void* const* d_in, const int* in_sizes, int n_in,
                              void* d_out, int out_size, void* d_ws, size_t ws_size,
                              hipStream_t stream)
{
    const void* V    = d_in[0];
    const void* Q    = d_in[1];
    const void* K    = d_in[2];
    const void* mask = d_in[3];
    const void* Wq = d_in[4];  const void* bq = d_in[5];
    const void* Wk = d_in[6];  const void* bk = d_in[7];
    const void* Wv = d_in[8];  const void* bv = d_in[9];
    const void* Wo = d_in[10]; const void* bo = d_in[11];
    float* out = (float*)d_out;

    char* ws = (char*)d_ws;
    int*    flagp = (int*)ws;                      // 128 B
    float*  biasf = (float*)(ws + 128);            // 1280 fp32
    ushort* qh  = (ushort*)(ws + 8192);            // each 1,048,576 ushorts (2 MB)
    ushort* kh  = qh  + 1048576;
    ushort* vh_ = kh  + 1048576;
    ushort* vT  = vh_ + 1048576;
    ushort* ctx = vT  + 1048576;
    ushort* Wt  = ctx + 1048576;                   // 393,216
    ushort* Wot = Wt  + 393216;                    // 131,072
    ushort* Xb  = Wot + 131072;                    // 6,291,456 ushorts (12.6 MB)
    // partials overlap Xb (Xb dead after qkv_gemm): 8.65 MB <= 12.6 MB
    float* pO = (float*)Xb;                        // 4096 waves x 512 fp32
    float* pl = pO + 4096 * 512;                   // 65,536 fp32

    detect_dtype<<<1, 64, 0, stream>>>((const ushort*)Q, flagp);
    convert_x<<<dim3(1024, 3), 256, 0, stream>>>(Q, K, V, flagp, Xb);
    transpose_w<<<513, 256, 0, stream>>>(Wq, Wk, Wv, Wo, bq, bk, bv, bo, flagp, Wt, Wot, biasf);
    qkv_gemm<<<dim3(128, 3), 256, 0, stream>>>(Xb, Wt, biasf, qh, kh, vh_);
    transpose_v<<<512, 256, 0, stream>>>(vh_, vT);
    attn<<<1024, 256, 0, stream>>>(qh, kh, vT, mask, flagp, pO, pl);
    combine<<<4096, 256, 0, stream>>>(pO, pl, ctx);
    out_proj<<<256, 256, 0, stream>>>(ctx, Wot, biasf, out);
}